// Round 1
// baseline (2492.848 us; speedup 1.0000x reference)
//
#include <hip/hip_runtime.h>
#include <math.h>

#define N_NODES 50000
#define N_EDGES 1600000
#define HID 128
#define NF 128
#define NG 50
#define NL 6
#define NSEG 64
#define TAB 2048
#define CUTOFF 20.0f
#define LOG2F_ 0.6931471805599453f

__device__ __forceinline__ float ssp(float x){
  // softplus(x) - log(2), numerically stable
  float sp = fmaxf(x, 0.f) + log1pf(expf(-fabsf(x)));
  return sp - LOG2F_;
}

// ---------------- edge distance ----------------
__global__ __launch_bounds__(256) void k_dist(const int* __restrict__ ei,
                                              const float* __restrict__ pos,
                                              float* __restrict__ dist){
  for (int e = blockIdx.x*blockDim.x + threadIdx.x; e < N_EDGES; e += gridDim.x*blockDim.x){
    int s = ei[e], t = ei[N_EDGES + e];
    float dx = pos[3*s]   - pos[3*t];
    float dy = pos[3*s+1] - pos[3*t+1];
    float dz = pos[3*s+2] - pos[3*t+2];
    dist[e] = sqrtf(dx*dx + dy*dy + dz*dz);
  }
}

// ---------------- CSR build ----------------
__global__ __launch_bounds__(256) void k_hist(const int* __restrict__ ei, int* __restrict__ deg){
  for (int e = blockIdx.x*blockDim.x + threadIdx.x; e < N_EDGES; e += gridDim.x*blockDim.x)
    atomicAdd(&deg[ei[N_EDGES + e]], 1);
}

__global__ __launch_bounds__(1024) void k_scan(const int* __restrict__ deg, int* __restrict__ row_start){
  __shared__ int sums[1024];
  const int t = threadIdx.x;
  const int CH = (N_NODES + 1023) / 1024; // 49
  const int base = t * CH;
  int s = 0;
  for (int i = 0; i < CH; i++){ int idx = base + i; if (idx < N_NODES) s += deg[idx]; }
  sums[t] = s; __syncthreads();
  for (int off = 1; off < 1024; off <<= 1){
    int v = (t >= off) ? sums[t - off] : 0;
    __syncthreads();
    sums[t] += v;
    __syncthreads();
  }
  int run = (t == 0) ? 0 : sums[t - 1];  // exclusive prefix
  for (int i = 0; i < CH; i++){
    int idx = base + i;
    if (idx < N_NODES){ row_start[idx] = run; run += deg[idx]; }
  }
  if (t == 1023) row_start[N_NODES] = run; // == N_EDGES
}

__global__ __launch_bounds__(256) void k_scatter(const int* __restrict__ ei,
                                                 const float* __restrict__ dist,
                                                 const int* __restrict__ row_start,
                                                 int* __restrict__ cursor,
                                                 int* __restrict__ csr_src,
                                                 float* __restrict__ csr_d){
  for (int e = blockIdx.x*blockDim.x + threadIdx.x; e < N_EDGES; e += gridDim.x*blockDim.x){
    int dn = ei[N_EDGES + e];
    int slot = atomicAdd(&cursor[dn], 1);
    int p = row_start[dn] + slot;
    csr_src[p] = ei[e];
    csr_d[p]   = dist[e];
  }
}

// ---------------- filter table: W_l(d) * C(d), sampled on TAB grid ----------------
__global__ __launch_bounds__(128) void k_table(const float* __restrict__ w1, const float* __restrict__ b1,
                                               const float* __restrict__ w2, const float* __restrict__ b2,
                                               float* __restrict__ tab){
  int l = blockIdx.x / TAB, j = blockIdx.x % TAB;
  int tid = threadIdx.x;
  float d = j * (CUTOFF / (TAB - 1));
  __shared__ float ea[NG];
  __shared__ float sbuf[NF];
  if (tid < NG){
    const float gstep = CUTOFF / (NG - 1);
    const float coeff = -0.5f / (gstep * gstep);
    float u = d - tid * gstep;
    ea[tid] = expf(coeff * u * u);
  }
  __syncthreads();
  float z = b1[l*NF + tid];
  for (int k = 0; k < NG; k++) z += ea[k] * w1[(l*NG + k)*NF + tid];
  sbuf[tid] = ssp(z);
  __syncthreads();
  float W = b2[l*NF + tid];
  for (int k = 0; k < NF; k++) W += sbuf[k] * w2[(l*NF + k)*NF + tid];
  float C = 0.5f * (cosf(d * (float)M_PI / CUTOFF) + 1.f);
  tab[((size_t)l*TAB + j)*NF + tid] = W * C;
}

// ---------------- hx = h @ conv_lin1_w[l] (8 nodes / block) ----------------
__global__ __launch_bounds__(128) void k_lin1(const float* __restrict__ h,
                                              const float* __restrict__ w,
                                              float* __restrict__ hx){
  int tid = threadIdx.x;
  int n0 = blockIdx.x * 8;
  __shared__ float hs[8][HID];
  #pragma unroll
  for (int r = 0; r < 8; r++) hs[r][tid] = h[(size_t)(n0 + r)*HID + tid];
  __syncthreads();
  float acc[8];
  #pragma unroll
  for (int r = 0; r < 8; r++) acc[r] = 0.f;
  for (int k = 0; k < HID; k++){
    float wv = w[k*NF + tid];
    #pragma unroll
    for (int r = 0; r < 8; r++) acc[r] += hs[r][k] * wv;
  }
  #pragma unroll
  for (int r = 0; r < 8; r++) hx[(size_t)(n0 + r)*NF + tid] = acc[r];
}

// ---------------- edge aggregation: agg[i] = sum_e W(d_e) * hx[src_e] ----------------
__global__ __launch_bounds__(128) void k_edgeagg(const int* __restrict__ row_start,
                                                 const int* __restrict__ csr_src,
                                                 const float* __restrict__ csr_d,
                                                 const float* __restrict__ tab_l,
                                                 const float* __restrict__ hx,
                                                 float* __restrict__ agg){
  int i = blockIdx.x;
  int tid = threadIdx.x;
  int rs = row_start[i], re = row_start[i + 1];
  const float INV_STEP = (TAB - 1) / CUTOFF;
  float acc = 0.f;
  for (int p = rs; p < re; ++p){
    int s = csr_src[p];
    float dv = csr_d[p];
    float t = dv * INV_STEP;
    t = fminf(fmaxf(t, 0.f), (float)(TAB - 1) - 0.001f);
    int i0 = (int)t;
    float fr = t - (float)i0;
    const float* t0 = tab_l + (size_t)i0 * NF + tid;
    float w0 = t0[0], w1v = t0[NF];
    float W = w0 + fr * (w1v - w0);
    acc += hx[(size_t)s * NF + tid] * W;
  }
  agg[(size_t)i * NF + tid] = acc;
}

// ---------------- node update: h += ssp(agg@w2b + b2b) @ linw + linb ----------------
__global__ __launch_bounds__(128) void k_node(const float* __restrict__ agg,
                                              const float* __restrict__ w2b, const float* __restrict__ b2b,
                                              const float* __restrict__ linw, const float* __restrict__ linb,
                                              float* __restrict__ h){
  int tid = threadIdx.x;
  int n0 = blockIdx.x * 8;
  __shared__ float a_s[8][NF];
  __shared__ float s_s[8][HID];
  #pragma unroll
  for (int r = 0; r < 8; r++) a_s[r][tid] = agg[(size_t)(n0 + r)*NF + tid];
  __syncthreads();
  float acc[8];
  #pragma unroll
  for (int r = 0; r < 8; r++) acc[r] = b2b[tid];
  for (int k = 0; k < NF; k++){
    float wv = w2b[k*HID + tid];
    #pragma unroll
    for (int r = 0; r < 8; r++) acc[r] += a_s[r][k] * wv;
  }
  #pragma unroll
  for (int r = 0; r < 8; r++) s_s[r][tid] = ssp(acc[r]);
  __syncthreads();
  #pragma unroll
  for (int r = 0; r < 8; r++) acc[r] = linb[tid];
  for (int k = 0; k < HID; k++){
    float wv = linw[k*HID + tid];
    #pragma unroll
    for (int r = 0; r < 8; r++) acc[r] += s_s[r][k] * wv;
  }
  #pragma unroll
  for (int r = 0; r < 8; r++) h[(size_t)(n0 + r)*HID + tid] += acc[r];
}

// ---------------- readout: o = ssp(h@o1w+o1b)@o2w+o2b, segment-sum by batch ----------------
__global__ __launch_bounds__(64) void k_out(const float* __restrict__ h,
                                            const float* __restrict__ w1, const float* __restrict__ b1,
                                            const float* __restrict__ w2, const float* __restrict__ b2,
                                            const int* __restrict__ batch, float* __restrict__ out){
  int tid = threadIdx.x;
  int n0 = blockIdx.x * 8;
  __shared__ float hs[8 * HID];
  for (int k = tid; k < 8 * HID; k += 64) hs[k] = h[(size_t)n0 * HID + k];
  __syncthreads();
  float acc[8];
  #pragma unroll
  for (int r = 0; r < 8; r++) acc[r] = b1[tid];
  for (int k = 0; k < HID; k++){
    float wv = w1[k*64 + tid];
    #pragma unroll
    for (int r = 0; r < 8; r++) acc[r] += hs[r*HID + k] * wv;
  }
  float w2v = w2[tid];
  float b2v = b2[0];
  #pragma unroll
  for (int r = 0; r < 8; r++){
    float p = ssp(acc[r]) * w2v;
    #pragma unroll
    for (int off = 32; off >= 1; off >>= 1) p += __shfl_xor(p, off);
    if (tid == 0) atomicAdd(&out[batch[n0 + r]], p + b2v);
  }
}

extern "C" void kernel_launch(void* const* d_in, const int* in_sizes, int n_in,
                              void* d_out, int out_size, void* d_ws, size_t ws_size,
                              hipStream_t stream) {
  const float* h     = (const float*)d_in[0];
  const float* pos   = (const float*)d_in[1];
  const int*   ei    = (const int*)d_in[2];
  const int*   batch = (const int*)d_in[3];
  const float* mlp_w1 = (const float*)d_in[4];
  const float* mlp_b1 = (const float*)d_in[5];
  const float* mlp_w2 = (const float*)d_in[6];
  const float* mlp_b2 = (const float*)d_in[7];
  const float* cl1w  = (const float*)d_in[8];
  const float* cl2w  = (const float*)d_in[9];
  const float* cl2b  = (const float*)d_in[10];
  const float* linw  = (const float*)d_in[11];
  const float* linb  = (const float*)d_in[12];
  const float* o1w   = (const float*)d_in[13];
  const float* o1b   = (const float*)d_in[14];
  const float* o2w   = (const float*)d_in[15];
  const float* o2b   = (const float*)d_in[16];
  float* out = (float*)d_out;

  float* fws   = (float*)d_ws;
  float* h_cur = fws;
  float* hx    = h_cur + (size_t)N_NODES*HID;
  float* agg   = hx    + (size_t)N_NODES*NF;
  float* dist  = agg   + (size_t)N_NODES*NF;
  float* csr_d = dist  + N_EDGES;
  float* tab   = csr_d + N_EDGES;
  int* csr_src   = (int*)(tab + (size_t)NL*TAB*NF);
  int* deg       = csr_src + N_EDGES;
  int* row_start = deg + N_NODES;
  int* cursor    = row_start + N_NODES + 1;

  hipMemsetAsync(out, 0, NSEG*sizeof(float), stream);
  hipMemsetAsync(deg, 0, N_NODES*sizeof(int), stream);
  hipMemsetAsync(cursor, 0, N_NODES*sizeof(int), stream);
  hipMemcpyAsync(h_cur, h, (size_t)N_NODES*HID*sizeof(float), hipMemcpyDeviceToDevice, stream);

  k_dist<<<2048, 256, 0, stream>>>(ei, pos, dist);
  k_hist<<<2048, 256, 0, stream>>>(ei, deg);
  k_scan<<<1, 1024, 0, stream>>>(deg, row_start);
  k_scatter<<<2048, 256, 0, stream>>>(ei, dist, row_start, cursor, csr_src, csr_d);
  k_table<<<NL*TAB, 128, 0, stream>>>(mlp_w1, mlp_b1, mlp_w2, mlp_b2, tab);

  for (int l = 0; l < NL; l++){
    k_lin1<<<N_NODES/8, 128, 0, stream>>>(h_cur, cl1w + (size_t)l*HID*NF, hx);
    k_edgeagg<<<N_NODES, 128, 0, stream>>>(row_start, csr_src, csr_d,
                                           tab + (size_t)l*TAB*NF, hx, agg);
    k_node<<<N_NODES/8, 128, 0, stream>>>(agg, cl2w + (size_t)l*NF*HID, cl2b + (size_t)l*HID,
                                          linw + (size_t)l*HID*HID, linb + (size_t)l*HID, h_cur);
  }
  k_out<<<N_NODES/8, 64, 0, stream>>>(h_cur, o1w, o1b, o2w, o2b, batch, out);
}

// Round 2
// 2206.322 us; speedup vs baseline: 1.1299x; 1.1299x over previous
//
#include <hip/hip_runtime.h>
#include <math.h>

#define N_NODES 50000
#define N_EDGES 1600000
#define HID 128
#define NF 128
#define NG 50
#define NL 6
#define NSEG 64
#define TAB 2048
#define CUTOFF 20.0f
#define LOG2F_ 0.6931471805599453f

__device__ __forceinline__ float ssp(float x){
  // softplus(x) - log(2), numerically stable
  float sp = fmaxf(x, 0.f) + log1pf(expf(-fabsf(x)));
  return sp - LOG2F_;
}

// ---------------- edge distance + degree histogram (fused) ----------------
__global__ __launch_bounds__(256) void k_dist(const int* __restrict__ ei,
                                              const float* __restrict__ pos,
                                              float* __restrict__ dist,
                                              int* __restrict__ deg){
  for (int e = blockIdx.x*blockDim.x + threadIdx.x; e < N_EDGES; e += gridDim.x*blockDim.x){
    int s = ei[e], t = ei[N_EDGES + e];
    float dx = pos[3*s]   - pos[3*t];
    float dy = pos[3*s+1] - pos[3*t+1];
    float dz = pos[3*s+2] - pos[3*t+2];
    dist[e] = sqrtf(dx*dx + dy*dy + dz*dz);
    atomicAdd(&deg[t], 1);
  }
}

__global__ __launch_bounds__(1024) void k_scan(const int* __restrict__ deg, int* __restrict__ row_start){
  __shared__ int sums[1024];
  const int t = threadIdx.x;
  const int CH = (N_NODES + 1023) / 1024; // 49
  const int base = t * CH;
  int s = 0;
  for (int i = 0; i < CH; i++){ int idx = base + i; if (idx < N_NODES) s += deg[idx]; }
  sums[t] = s; __syncthreads();
  for (int off = 1; off < 1024; off <<= 1){
    int v = (t >= off) ? sums[t - off] : 0;
    __syncthreads();
    sums[t] += v;
    __syncthreads();
  }
  int run = (t == 0) ? 0 : sums[t - 1];  // exclusive prefix
  for (int i = 0; i < CH; i++){
    int idx = base + i;
    if (idx < N_NODES){ row_start[idx] = run; run += deg[idx]; }
  }
  if (t == 1023) row_start[N_NODES] = run; // == N_EDGES
}

__global__ __launch_bounds__(256) void k_scatter(const int* __restrict__ ei,
                                                 const float* __restrict__ dist,
                                                 const int* __restrict__ row_start,
                                                 int* __restrict__ cursor,
                                                 int* __restrict__ csr_src,
                                                 float* __restrict__ csr_d){
  for (int e = blockIdx.x*blockDim.x + threadIdx.x; e < N_EDGES; e += gridDim.x*blockDim.x){
    int dn = ei[N_EDGES + e];
    int slot = atomicAdd(&cursor[dn], 1);
    int p = row_start[dn] + slot;
    csr_src[p] = ei[e];
    csr_d[p]   = dist[e];
  }
}

// ---------------- filter table: W_l(d) * C(d), sampled on TAB grid ----------------
__global__ __launch_bounds__(128) void k_table(const float* __restrict__ w1, const float* __restrict__ b1,
                                               const float* __restrict__ w2, const float* __restrict__ b2,
                                               float* __restrict__ tab){
  int l = blockIdx.x / TAB, j = blockIdx.x % TAB;
  int tid = threadIdx.x;
  float d = j * (CUTOFF / (TAB - 1));
  __shared__ float ea[NG];
  __shared__ float sbuf[NF];
  if (tid < NG){
    const float gstep = CUTOFF / (NG - 1);
    const float coeff = -0.5f / (gstep * gstep);
    float u = d - tid * gstep;
    ea[tid] = expf(coeff * u * u);
  }
  __syncthreads();
  float z = b1[l*NF + tid];
  for (int k = 0; k < NG; k++) z += ea[k] * w1[(l*NG + k)*NF + tid];
  sbuf[tid] = ssp(z);
  __syncthreads();
  float W = b2[l*NF + tid];
  for (int k = 0; k < NF; k++) W += sbuf[k] * w2[(l*NF + k)*NF + tid];
  float C = 0.5f * (cosf(d * (float)M_PI / CUTOFF) + 1.f);
  tab[((size_t)l*TAB + j)*NF + tid] = W * C;
}

// ---------------- hx = h @ conv_lin1_w[l] (8 nodes / block) ----------------
__global__ __launch_bounds__(128) void k_lin1(const float* __restrict__ h,
                                              const float* __restrict__ w,
                                              float* __restrict__ hx){
  int tid = threadIdx.x;
  int n0 = blockIdx.x * 8;
  __shared__ float hs[8][HID];
  #pragma unroll
  for (int r = 0; r < 8; r++) hs[r][tid] = h[(size_t)(n0 + r)*HID + tid];
  __syncthreads();
  float acc[8];
  #pragma unroll
  for (int r = 0; r < 8; r++) acc[r] = 0.f;
  for (int k = 0; k < HID; k++){
    float wv = w[k*NF + tid];
    #pragma unroll
    for (int r = 0; r < 8; r++) acc[r] += hs[r][k] * wv;
  }
  #pragma unroll
  for (int r = 0; r < 8; r++) hx[(size_t)(n0 + r)*NF + tid] = acc[r];
}

// ---------------- edge aggregation: agg[i] = sum_e W(d_e) * hx[src_e] ----------------
__global__ __launch_bounds__(128) void k_edgeagg(const int* __restrict__ row_start,
                                                 const int* __restrict__ csr_src,
                                                 const float* __restrict__ csr_d,
                                                 const float* __restrict__ tab_l,
                                                 const float* __restrict__ hx,
                                                 float* __restrict__ agg){
  int i = blockIdx.x;
  int tid = threadIdx.x;
  int rs = row_start[i], re = row_start[i + 1];
  const float INV_STEP = (TAB - 1) / CUTOFF;
  float acc = 0.f;
  for (int p = rs; p < re; ++p){
    int s = csr_src[p];
    float dv = csr_d[p];
    float t = dv * INV_STEP;
    t = fminf(fmaxf(t, 0.f), (float)(TAB - 1) - 0.001f);
    int i0 = (int)t;
    float fr = t - (float)i0;
    const float* t0 = tab_l + (size_t)i0 * NF + tid;
    float w0 = t0[0], w1v = t0[NF];
    float W = w0 + fr * (w1v - w0);
    acc += hx[(size_t)s * NF + tid] * W;
  }
  agg[(size_t)i * NF + tid] = acc;
}

// ---------------- node update: h += ssp(agg@w2b + b2b) @ linw + linb ----------------
__global__ __launch_bounds__(128) void k_node(const float* __restrict__ agg,
                                              const float* __restrict__ w2b, const float* __restrict__ b2b,
                                              const float* __restrict__ linw, const float* __restrict__ linb,
                                              float* __restrict__ h){
  int tid = threadIdx.x;
  int n0 = blockIdx.x * 8;
  __shared__ float a_s[8][NF];
  __shared__ float s_s[8][HID];
  #pragma unroll
  for (int r = 0; r < 8; r++) a_s[r][tid] = agg[(size_t)(n0 + r)*NF + tid];
  __syncthreads();
  float acc[8];
  #pragma unroll
  for (int r = 0; r < 8; r++) acc[r] = b2b[tid];
  for (int k = 0; k < NF; k++){
    float wv = w2b[k*HID + tid];
    #pragma unroll
    for (int r = 0; r < 8; r++) acc[r] += a_s[r][k] * wv;
  }
  #pragma unroll
  for (int r = 0; r < 8; r++) s_s[r][tid] = ssp(acc[r]);
  __syncthreads();
  #pragma unroll
  for (int r = 0; r < 8; r++) acc[r] = linb[tid];
  for (int k = 0; k < HID; k++){
    float wv = linw[k*HID + tid];
    #pragma unroll
    for (int r = 0; r < 8; r++) acc[r] += s_s[r][k] * wv;
  }
  #pragma unroll
  for (int r = 0; r < 8; r++) h[(size_t)(n0 + r)*HID + tid] += acc[r];
}

// ---------------- readout: contiguous chunk per wave, run-length segment sum ----------------
// 256 blocks x 256 threads = 1024 waves; each wave owns ~49 contiguous nodes.
__global__ __launch_bounds__(256) void k_out(const float* __restrict__ h,
                                             const float* __restrict__ w1, const float* __restrict__ b1,
                                             const float* __restrict__ w2, const float* __restrict__ b2,
                                             const int* __restrict__ batch, float* __restrict__ out){
  __shared__ float w1s[HID * 64];
  int tid = threadIdx.x;
  for (int k = tid; k < HID * 64; k += 256) w1s[k] = w1[k];
  __syncthreads();
  int wave = tid >> 6, lane = tid & 63;
  int gwave = blockIdx.x * 4 + wave;
  const int NWAVES = 256 * 4;
  const int CHUNK = (N_NODES + NWAVES - 1) / NWAVES; // 49
  int n0 = gwave * CHUNK;
  int n1 = n0 + CHUNK; if (n1 > N_NODES) n1 = N_NODES;
  float b1v = b1[lane];
  float w2v = w2[lane];
  float b2v = b2[0];
  float run = 0.f; int curseg = -1;
  for (int n = n0; n < n1; ++n){
    float h0 = h[(size_t)n * HID + lane];
    float h1 = h[(size_t)n * HID + 64 + lane];
    float acc = b1v;
    #pragma unroll
    for (int k = 0; k < 64; k++){
      float hb = __shfl(h0, k);
      acc += hb * w1s[k * 64 + lane];
    }
    #pragma unroll
    for (int k = 0; k < 64; k++){
      float hb = __shfl(h1, k);
      acc += hb * w1s[(64 + k) * 64 + lane];
    }
    float p = ssp(acc) * w2v;
    #pragma unroll
    for (int off = 32; off >= 1; off >>= 1) p += __shfl_xor(p, off);
    if (lane == 0){
      int seg = batch[n];
      if (seg != curseg){
        if (curseg >= 0) atomicAdd(&out[curseg], run);
        curseg = seg; run = 0.f;
      }
      run += p + b2v;
    }
  }
  if (lane == 0 && curseg >= 0) atomicAdd(&out[curseg], run);
}

extern "C" void kernel_launch(void* const* d_in, const int* in_sizes, int n_in,
                              void* d_out, int out_size, void* d_ws, size_t ws_size,
                              hipStream_t stream) {
  const float* h     = (const float*)d_in[0];
  const float* pos   = (const float*)d_in[1];
  const int*   ei    = (const int*)d_in[2];
  const int*   batch = (const int*)d_in[3];
  const float* mlp_w1 = (const float*)d_in[4];
  const float* mlp_b1 = (const float*)d_in[5];
  const float* mlp_w2 = (const float*)d_in[6];
  const float* mlp_b2 = (const float*)d_in[7];
  const float* cl1w  = (const float*)d_in[8];
  const float* cl2w  = (const float*)d_in[9];
  const float* cl2b  = (const float*)d_in[10];
  const float* linw  = (const float*)d_in[11];
  const float* linb  = (const float*)d_in[12];
  const float* o1w   = (const float*)d_in[13];
  const float* o1b   = (const float*)d_in[14];
  const float* o2w   = (const float*)d_in[15];
  const float* o2b   = (const float*)d_in[16];
  float* out = (float*)d_out;

  float* fws   = (float*)d_ws;
  float* h_cur = fws;
  float* hx    = h_cur + (size_t)N_NODES*HID;
  float* agg   = hx    + (size_t)N_NODES*NF;
  float* dist  = agg   + (size_t)N_NODES*NF;
  float* csr_d = dist  + N_EDGES;
  float* tab   = csr_d + N_EDGES;
  int* csr_src   = (int*)(tab + (size_t)NL*TAB*NF);
  int* deg       = csr_src + N_EDGES;
  int* row_start = deg + N_NODES;
  int* cursor    = row_start + N_NODES + 1;

  hipMemsetAsync(out, 0, NSEG*sizeof(float), stream);
  hipMemsetAsync(deg, 0, N_NODES*sizeof(int), stream);
  hipMemsetAsync(cursor, 0, N_NODES*sizeof(int), stream);
  hipMemcpyAsync(h_cur, h, (size_t)N_NODES*HID*sizeof(float), hipMemcpyDeviceToDevice, stream);

  k_dist<<<2048, 256, 0, stream>>>(ei, pos, dist, deg);
  k_scan<<<1, 1024, 0, stream>>>(deg, row_start);
  k_scatter<<<2048, 256, 0, stream>>>(ei, dist, row_start, cursor, csr_src, csr_d);
  k_table<<<NL*TAB, 128, 0, stream>>>(mlp_w1, mlp_b1, mlp_w2, mlp_b2, tab);

  for (int l = 0; l < NL; l++){
    k_lin1<<<N_NODES/8, 128, 0, stream>>>(h_cur, cl1w + (size_t)l*HID*NF, hx);
    k_edgeagg<<<N_NODES, 128, 0, stream>>>(row_start, csr_src, csr_d,
                                           tab + (size_t)l*TAB*NF, hx, agg);
    k_node<<<N_NODES/8, 128, 0, stream>>>(agg, cl2w + (size_t)l*NF*HID, cl2b + (size_t)l*HID,
                                          linw + (size_t)l*HID*HID, linb + (size_t)l*HID, h_cur);
  }
  k_out<<<256, 256, 0, stream>>>(h_cur, o1w, o1b, o2w, o2b, batch, out);
}